// Round 12
// baseline (2993.176 us; speedup 1.0000x reference)
//
#include <hip/hip_runtime.h>

// ---------------------------------------------------------------------------
// gmm_hyper_y2 on MI355X: bf16 MFMA implicit-GEMM convs, NHWC bf16 acts,
// frag-order weights (global->reg), branch-fused dispatches.
// R12: 256-thr blocks (4 waves = 2 co-halves x 2 rows) + launch_bounds(256,3).
// R10/R11 post-mortem: unified regs = acc(96 AGPR)+arch(128) = 224/wave ->
// 2 waves/SIMD; 8-wave blocks quantize occupancy to 1 block/CU. Small
// independent blocks + reg cap 170 (arch<=74) -> 3 blocks/CU, cross-block
// overlap of stage-drain/weights/ds with MFMA. Spill signature = FETCH/WRITE
// balloon (known from R6/R8) -> revert cap if seen.
// ---------------------------------------------------------------------------

typedef __attribute__((ext_vector_type(8))) short   short8;
typedef __attribute__((ext_vector_type(4))) float   f32x4;
typedef __attribute__((ext_vector_type(4))) unsigned short u16x4;

#define DEV __device__ __forceinline__
#define AS1 __attribute__((address_space(1)))
#define AS3 __attribute__((address_space(3)))

DEV unsigned short f2bf(float f) {           // RTNE f32 -> bf16
  union { float f; unsigned u; } v; v.f = f;
  unsigned u = v.u;
  u += 0x7fffu + ((u >> 16) & 1u);
  return (unsigned short)(u >> 16);
}

// ---------------- weight prep: OIHW f32 -> frag-order bf16 -----------------
// dst layout: [tap(25)][kt(CIN/32)][mt(COUTP/16)][lane(64)][j(8)]
template<int CIN, int COUT, int COUTP>
__global__ void prep_w(const float* __restrict__ w, unsigned short* __restrict__ dst) {
  const int KT = CIN / 32, MT = COUTP / 16;
  const int total = 25 * KT * MT * 512;
  for (int idx = blockIdx.x * blockDim.x + threadIdx.x; idx < total;
       idx += gridDim.x * blockDim.x) {
    int j   = idx & 7;
    int l   = (idx >> 3) & 63;
    int blk = idx >> 9;
    int mt  = blk % MT;
    int rst = blk / MT;
    int kt  = rst % KT;
    int tap = rst / KT;
    int ky = tap / 5, kx = tap % 5;
    int co = mt * 16 + (l & 15);
    int ci = kt * 32 + (l >> 4) * 8 + j;
    float val = (co < COUT) ? w[((co * CIN + ci) * 5 + ky) * 5 + kx] : 0.0f;
    dst[idx] = f2bf(val);
  }
}

// ------------- upsample z2 x4 bilinear + concat y1 -> NHWC bf16 ------------
__global__ void upsample_cat_k(const float* __restrict__ z2,
                               const float* __restrict__ y1,
                               unsigned short* __restrict__ cat) {
  int tid = blockIdx.x * blockDim.x + threadIdx.x;
  int p = tid % 9216;
  int rest = tid / 9216;
  int chunk = rest % 40;
  int b = rest / 40;
  if (b >= 8) return;
  int Y = p / 96, X = p % 96;
  short8 vec;
  if (chunk < 16) {
    const float s = 23.0f / 95.0f;
    float ys = Y * s, xs = X * s;
    float fy = floorf(ys), fx = floorf(xs);
    int y0 = (int)fy, x0 = (int)fx;
    int y1i = min(y0 + 1, 23), x1i = min(x0 + 1, 23);
    float wy = ys - fy, wx = xs - fx;
    int c0 = chunk * 8;
    const float* zb = z2 + ((size_t)b * 128 + c0) * 576;
#pragma unroll
    for (int i = 0; i < 8; ++i) {
      const float* zc = zb + (size_t)i * 576;
      float g00 = zc[y0 * 24 + x0],  g01 = zc[y0 * 24 + x1i];
      float g10 = zc[y1i * 24 + x0], g11 = zc[y1i * 24 + x1i];
      float top = g00 + (g01 - g00) * wx;
      float bot = g10 + (g11 - g10) * wx;
      vec[i] = (short)f2bf(top + (bot - top) * wy);
    }
  } else {
    int c0 = (chunk - 16) * 8;
    const float* yb = y1 + ((size_t)b * 192 + c0) * 9216 + p;
#pragma unroll
    for (int i = 0; i < 8; ++i) vec[i] = (short)f2bf(yb[(size_t)i * 9216]);
  }
  int cbase = (chunk < 16) ? chunk * 8 : 128 + (chunk - 16) * 8;
  *reinterpret_cast<short8*>(cat + ((size_t)(b * 9216 + p)) * 320 + cbase) = vec;
}

// --------------------------- 5x5 conv, pad 2 --------------------------------
// Block: 256 thr = 4 waves; wave (wm, wr) = (co-half 0..1, row 0..1).
// Wave tile: 4 co-frags x 6 px-frags (64 co x 96 px) -> acc 96 regs (AGPR).
// Block: 128 co x 2 rows x 96 px. LDS: 40 KB (6 rows x 100 px x 32ci, padded
// to 2560 slots); stage->barrier->compute->barrier; 3 blocks/CU target.
// Bijective XCD swizzle, coblk outermost (weight slice per-XCD L2-resident).
struct BranchArgs {
  const unsigned short* in[3];
  const unsigned short* w[3];
  const float* bias[3];
  unsigned short* ob[3];
  float* of[3];
};

template<int CIN, int COUT, int COUTP, int ACT0, int ACT1, int ACT2, int OUTMODE>
DEV void conv5_body(BranchArgs args, const char* __restrict__ zp) {
  const int KT = CIN / 32, MT = COUTP / 16;
  __shared__ alignas(16) char lds[40960];      // 2560 chunks x 16 B (2400 used)
  const int tid = threadIdx.x;                 // 0..255
  const int l = tid & 63;
  const int wid = tid >> 6;                    // 0..3
  const int wm = wid & 1;                      // co-half
  const int wr = wid >> 1;                     // output row 0..1
  const int lj = l >> 4, lx = l & 15;

  // ---- bijective XCD-aware block swizzle ----
  const int Zd = gridDim.y;                    // batch*branch count
  const int T = 48 * Zd * gridDim.z;           // total blocks (always %8==0)
  int f = blockIdx.x + 48 * (blockIdx.y + Zd * blockIdx.z);
  int fp = (f & 7) * (T >> 3) + (f >> 3);
  const int rowtile = fp % 48;
  int rest = fp / 48;
  const int bz = rest % Zd;
  const int coblk = (rest / Zd) * 128;
  const int b = bz & 7, br = bz >> 3;
  const int y0 = rowtile * 2;

  const unsigned short* act_in = args.in[br];
  const unsigned short* wfrag  = args.w[br];
  const int act = (br == 0) ? ACT0 : (br == 1 ? ACT1 : ACT2);

  // ---- per-thread staging descriptors (10 chunks of 16 B; slots 2400..2559 pad) ----
  int boff[10];
  unsigned okm = 0;
#pragma unroll
  for (int i = 0; i < 10; ++i) {
    int t = tid + i * 256;
    boff[i] = 0;
    if (t < 2400) {
      int p = t >> 2, q = t & 3;
      int r = p / 100, c = p - r * 100;
      int yy = y0 + r - 2, xx = c - 2;
      int ch = q ^ ((c >> 1) & 3);
      if ((unsigned)yy < 96u && (unsigned)xx < 96u) {
        boff[i] = ((b * 96 + yy) * 96 + xx) * CIN * 2 + ch * 16;
        okm |= 1u << i;
      }
    }
  }
  const char* actc = (const char*)act_in;

  f32x4 acc[4][6];
#pragma unroll
  for (int m = 0; m < 4; ++m)
#pragma unroll
    for (int n = 0; n < 6; ++n) acc[m][n] = f32x4{0.f, 0.f, 0.f, 0.f};

  auto stage = [&](int ktoff) {
#pragma unroll
    for (int i = 0; i < 10; ++i) {
      const char* s = ((okm >> i) & 1) ? (actc + boff[i] + ktoff) : zp;
      __builtin_amdgcn_global_load_lds(
          (const AS1 unsigned int*)s,
          (AS3 unsigned int*)(lds + (tid + i * 256) * 16), 16, 0, 0);
    }
  };

  const int mt0 = (coblk >> 4) + wm * 4;
  for (int kt = 0; kt < KT; ++kt) {
    stage(kt * 64);       // prev-iter reads finished at loop-tail barrier
    __syncthreads();      // drains vmcnt -> buf staged
    const unsigned short* wb = wfrag + ((size_t)kt * MT + mt0) * 512 + l * 8;
#pragma unroll
    for (int ky = 0; ky < 5; ++ky) {
      const int r = wr + ky;
#pragma unroll
      for (int kx = 0; kx < 5; ++kx) {
        const int tap = ky * 5 + kx;
        short8 aW[4];
#pragma unroll
        for (int m = 0; m < 4; ++m)
          aW[m] = *reinterpret_cast<const short8*>(wb + ((size_t)tap * KT * MT + m) * 512);
#pragma unroll
        for (int n = 0; n < 6; ++n) {
          int c = kx + n * 16 + lx;
          int off = ((r * 100 + c) << 6) + ((lj ^ ((c >> 1) & 3)) << 4);
          short8 bA = *reinterpret_cast<const short8*>(lds + off);
#pragma unroll
          for (int m = 0; m < 4; ++m)
            acc[m][n] = __builtin_amdgcn_mfma_f32_16x16x32_bf16(aW[m], bA, acc[m][n], 0, 0, 0);
        }
      }
    }
    __syncthreads();      // all LDS reads done before next stage overwrites
  }

  const int yout = y0 + wr;
  if (OUTMODE == 0) {
    unsigned short* ob = args.ob[br];
#pragma unroll
    for (int m = 0; m < 4; ++m) {
      int co0 = coblk + wm * 64 + m * 16 + lj * 4;
      f32x4 bv = *reinterpret_cast<const f32x4*>(args.bias[br] + co0);
#pragma unroll
      for (int n = 0; n < 6; ++n) {
        int x = n * 16 + lx;
        u16x4 pk;
#pragma unroll
        for (int j = 0; j < 4; ++j) {
          float v = acc[m][n][j] + bv[j];
          if (act == 1) v = fmaxf(v, 0.f);
          if (act == 2) v = (v >= 0.f) ? v : 0.01f * v;
          pk[j] = f2bf(v);
        }
        *reinterpret_cast<u16x4*>(ob + (size_t)((b * 96 + yout) * 96 + x) * COUT + co0) = pk;
      }
    }
  } else if (OUTMODE == 1) {
    // --- dense f32 NCHW epilogue: per-wave LDS slab transpose (4x6.4KB=25.6KB) ---
    float* of = args.of[br];
    float* slab = reinterpret_cast<float*>(lds) + wid * 1600;  // 16 x 100 f32
    const int co_r = l >> 2;                   // 0..15
    const int xs   = (l & 3) * 24;             // 0,24,48,72
#pragma unroll
    for (int m = 0; m < 4; ++m) {
      int mco = coblk + wm * 64 + m * 16;
      if (mco < COUT) {
        f32x4 bv = *reinterpret_cast<const f32x4*>(args.bias[br] + mco + lj * 4);
#pragma unroll
        for (int n = 0; n < 6; ++n)
#pragma unroll
          for (int j = 0; j < 4; ++j) {
            float v = acc[m][n][j] + bv[j];
            if (act == 1) v = fmaxf(v, 0.f);
            if (act == 2) v = (v >= 0.f) ? v : 0.01f * v;
            slab[(lj * 4 + j) * 100 + n * 16 + lx] = v;
          }
        asm volatile("s_waitcnt lgkmcnt(0)" ::: "memory");
        __builtin_amdgcn_sched_barrier(0);
        const float* srow = slab + co_r * 100 + xs;
        float* drow = of + ((size_t)(b * COUT + mco + co_r) * 96 + yout) * 96 + xs;
#pragma unroll
        for (int k = 0; k < 6; ++k)
          *reinterpret_cast<f32x4*>(drow + 4 * k) =
              *reinterpret_cast<const f32x4*>(srow + 4 * k);
        asm volatile("s_waitcnt lgkmcnt(0)" ::: "memory");
        __builtin_amdgcn_sched_barrier(0);
      }
    }
  } else {  // OUTMODE == 2: conv+bias -> per-row max partials
    float* part = args.of[0];
#pragma unroll
    for (int m = 0; m < 4; ++m) {
      int co0 = coblk + wm * 64 + m * 16 + lj * 4;
      f32x4 bv = f32x4{0.f, 0.f, 0.f, 0.f};
      if (co0 < COUT) bv = *reinterpret_cast<const f32x4*>(args.bias[br] + co0);
#pragma unroll
      for (int j = 0; j < 4; ++j) {
        float mx = -3.0e38f;
#pragma unroll
        for (int n = 0; n < 6; ++n) mx = fmaxf(mx, acc[m][n][j] + bv[j]);
#pragma unroll
        for (int s = 1; s < 16; s <<= 1) mx = fmaxf(mx, __shfl_xor(mx, s, 64));
        if (lx == 0 && co0 + j < COUT)
          part[(size_t)(b * COUT + co0 + j) * 96 + rowtile * 2 + wr] = mx;
      }
    }
  }
}

// ---- distinct kernel names per layer (profiler attribution) ----
__global__ __launch_bounds__(256, 3) void conv_l1(BranchArgs a, const char* __restrict__ zp) {
  conv5_body<320, 128, 128, 1, 2, 2, 0>(a, zp);
}
__global__ __launch_bounds__(256, 3) void conv_l2(BranchArgs a, const char* __restrict__ zp) {
  conv5_body<128, 128, 128, 1, 2, 0, 0>(a, zp);
}
__global__ __launch_bounds__(256, 3) void conv_l2w(BranchArgs a, const char* __restrict__ zp) {
  conv5_body<128, 576, 640, 0, 0, 0, 2>(a, zp);
}
__global__ __launch_bounds__(256, 3) void conv_l3(BranchArgs a, const char* __restrict__ zp) {
  conv5_body<128, 576, 640, 1, 0, 0, 1>(a, zp);
}

// --------------------- tail: reduce / 1x1 conv / softmax -------------------
__global__ void reduce_max_k(const float* __restrict__ part, float* __restrict__ pooled) {
  int i = blockIdx.x * blockDim.x + threadIdx.x;
  if (i >= 8 * 576) return;
  const float* p = part + (size_t)i * 96;
  float mx = p[0];
  for (int t = 1; t < 96; ++t) mx = fmaxf(mx, p[t]);
  pooled[i] = mx;
}

__global__ void tail_k(const float* __restrict__ pooled,
                       const float* __restrict__ ww3, const float* __restrict__ bw3,
                       float* __restrict__ outw) {
  __shared__ float g[576];
  __shared__ float h2[576];
  int b = blockIdx.x, tid = threadIdx.x;
  for (int i = tid; i < 576; i += 256) {
    float v = pooled[b * 576 + i];
    g[i] = (v >= 0.f) ? v : 0.01f * v;
  }
  __syncthreads();
  for (int o = tid; o < 576; o += 256) {
    float s = bw3[o];
    const float* wr = ww3 + (size_t)o * 576;
    for (int i = 0; i < 576; ++i) s += wr[i] * g[i];
    h2[o] = s;
  }
  __syncthreads();
  for (int m = tid; m < 192; m += 256) {
    float a0 = h2[m], a1 = h2[192 + m], a2 = h2[384 + m];
    float mx = fmaxf(a0, fmaxf(a1, a2));
    float e0 = expf(a0 - mx), e1 = expf(a1 - mx), e2 = expf(a2 - mx);
    float inv = 1.f / (e0 + e1 + e2);
    outw[b * 576 + m]       = e0 * inv;
    outw[b * 576 + 192 + m] = e1 * inv;
    outw[b * 576 + 384 + m] = e2 * inv;
  }
}

// ---------------------------------------------------------------------------
extern "C" void kernel_launch(void* const* d_in, const int* in_sizes, int n_in,
                              void* d_out, int out_size, void* d_ws, size_t ws_size,
                              hipStream_t stream) {
  const float* z2  = (const float*)d_in[0];
  const float* y1  = (const float*)d_in[1];
  const float* ws1 = (const float*)d_in[2];  const float* bs1 = (const float*)d_in[3];
  const float* ws2 = (const float*)d_in[4];  const float* bs2 = (const float*)d_in[5];
  const float* ws3 = (const float*)d_in[6];  const float* bs3 = (const float*)d_in[7];
  const float* wm1 = (const float*)d_in[8];  const float* bm1 = (const float*)d_in[9];
  const float* wm2 = (const float*)d_in[10]; const float* bm2 = (const float*)d_in[11];
  const float* wm3 = (const float*)d_in[12]; const float* bm3 = (const float*)d_in[13];
  const float* ww1 = (const float*)d_in[14]; const float* bw1 = (const float*)d_in[15];
  const float* ww2 = (const float*)d_in[16]; const float* bw2 = (const float*)d_in[17];
  const float* ww3 = (const float*)d_in[18]; const float* bw3 = (const float*)d_in[19];

  char* ws = (char*)d_ws;
  size_t off = 0;
  auto alloc = [&](size_t bytes) -> char* {
    char* p = ws + off;
    off += (bytes + 255) & ~(size_t)255;
    return p;
  };
  char* zp = alloc(4096);
  unsigned short* cat = (unsigned short*)alloc(8ull * 9216 * 320 * 2);
  unsigned short* t1s = (unsigned short*)alloc(8ull * 9216 * 128 * 2);
  unsigned short* t1m = (unsigned short*)alloc(8ull * 9216 * 128 * 2);
  unsigned short* t1w = (unsigned short*)alloc(8ull * 9216 * 128 * 2);
  const size_t szA = 25ull * 10 * 8 * 512;
  const size_t szB = 25ull * 4 * 8 * 512;
  const size_t szC = 25ull * 4 * 40 * 512;
  unsigned short* Ws1 = (unsigned short*)alloc(szA * 2);
  unsigned short* Ws2 = (unsigned short*)alloc(szB * 2);
  unsigned short* Ws3 = (unsigned short*)alloc(szC * 2);
  unsigned short* Wm1 = (unsigned short*)alloc(szA * 2);
  unsigned short* Wm2 = (unsigned short*)alloc(szB * 2);
  unsigned short* Wm3 = (unsigned short*)alloc(szC * 2);
  unsigned short* Ww1 = (unsigned short*)alloc(szA * 2);
  unsigned short* Ww2 = (unsigned short*)alloc(szC * 2);
  float* part   = (float*)alloc(8ull * 576 * 96 * 4);
  float* pooled = (float*)alloc(8ull * 576 * 4);
  // t2 buffers alias cat (fusedA finishes reading cat before fusedB writes t2)
  unsigned short* t2s = cat;
  unsigned short* t2m = cat + 8ull * 9216 * 128;

  float* out_sigma = (float*)d_out;
  float* out_means = out_sigma + 8ull * 576 * 9216;
  float* out_w     = out_means + 8ull * 576 * 9216;

  hipMemsetAsync(zp, 0, 4096, stream);

  prep_w<320, 128, 128><<<256, 256, 0, stream>>>(ws1, Ws1);
  prep_w<128, 128, 128><<<128, 256, 0, stream>>>(ws2, Ws2);
  prep_w<128, 576, 640><<<512, 256, 0, stream>>>(ws3, Ws3);
  prep_w<320, 128, 128><<<256, 256, 0, stream>>>(wm1, Wm1);
  prep_w<128, 128, 128><<<128, 256, 0, stream>>>(wm2, Wm2);
  prep_w<128, 576, 640><<<512, 256, 0, stream>>>(wm3, Wm3);
  prep_w<320, 128, 128><<<256, 256, 0, stream>>>(ww1, Ww1);
  prep_w<128, 576, 640><<<512, 256, 0, stream>>>(ww2, Ww2);

  upsample_cat_k<<<11520, 256, 0, stream>>>(z2, y1, cat);

  dim3 blk(256);

  // fused layer 1: sigma(relu) / means(lrelu) / weights(lrelu), cat -> t1*
  {
    BranchArgs a{};
    a.in[0] = cat; a.in[1] = cat; a.in[2] = cat;
    a.w[0] = Ws1; a.w[1] = Wm1; a.w[2] = Ww1;
    a.bias[0] = bs1; a.bias[1] = bm1; a.bias[2] = bw1;
    a.ob[0] = t1s; a.ob[1] = t1m; a.ob[2] = t1w;
    conv_l1<<<dim3(48, 24, 1), blk, 0, stream>>>(a, zp);
  }
  // fused layer 2: sigma(relu) / means(lrelu), t1* -> t2*
  {
    BranchArgs a{};
    a.in[0] = t1s; a.in[1] = t1m;
    a.w[0] = Ws2; a.w[1] = Wm2;
    a.bias[0] = bs2; a.bias[1] = bm2;
    a.ob[0] = t2s; a.ob[1] = t2m;
    conv_l2<<<dim3(48, 16, 1), blk, 0, stream>>>(a, zp);
  }
  // weights layer 2 conv + global-max partials (t1w -> part)
  {
    BranchArgs a{};
    a.in[0] = t1w;
    a.w[0] = Ww2;
    a.bias[0] = bw2;
    a.of[0] = part;
    conv_l2w<<<dim3(48, 8, 5), blk, 0, stream>>>(a, zp);
  }
  // fused layer 3: sigma(relu, f32) / means(none, f32), t2* -> d_out
  {
    BranchArgs a{};
    a.in[0] = t2s; a.in[1] = t2m;
    a.w[0] = Ws3; a.w[1] = Wm3;
    a.bias[0] = bs3; a.bias[1] = bm3;
    a.of[0] = out_sigma; a.of[1] = out_means;
    conv_l3<<<dim3(48, 16, 5), blk, 0, stream>>>(a, zp);
  }

  reduce_max_k<<<18, 256, 0, stream>>>(part, pooled);
  tail_k<<<8, 256, 0, stream>>>(pooled, ww3, bw3, out_w);
}

// Round 13
// 1459.278 us; speedup vs baseline: 2.0511x; 2.0511x over previous
//
#include <hip/hip_runtime.h>

// ---------------------------------------------------------------------------
// gmm_hyper_y2 on MI355X: bf16 MFMA implicit-GEMM convs, NHWC bf16 acts,
// frag-order weights (global->reg), branch-fused dispatches.
// R13: wave tile m4n3 (acc 48) -> 4-wave blocks (2 co-halves x 2 px-halves),
// 128co x 1row x 96px per block, launch_bounds(256,3) -> 3 blocks/CU.
// R12 post-mortem: 170-reg cap with acc=96 forced arch to 84 -> spills
// (FETCH/WRITE 1.17/0.83 GB). acc 48 + arch ~115 = ~163 <= 170 -> fits.
// Per-CU/tap at 12 waves: MFMA 698 cyc > weights-L2 375 > ds 423 -> MFMA-bound.
// ---------------------------------------------------------------------------

typedef __attribute__((ext_vector_type(8))) short   short8;
typedef __attribute__((ext_vector_type(4))) float   f32x4;
typedef __attribute__((ext_vector_type(4))) unsigned short u16x4;

#define DEV __device__ __forceinline__
#define AS1 __attribute__((address_space(1)))
#define AS3 __attribute__((address_space(3)))

DEV unsigned short f2bf(float f) {           // RTNE f32 -> bf16
  union { float f; unsigned u; } v; v.f = f;
  unsigned u = v.u;
  u += 0x7fffu + ((u >> 16) & 1u);
  return (unsigned short)(u >> 16);
}

// ---------------- weight prep: OIHW f32 -> frag-order bf16 -----------------
// dst layout: [tap(25)][kt(CIN/32)][mt(COUTP/16)][lane(64)][j(8)]
template<int CIN, int COUT, int COUTP>
__global__ void prep_w(const float* __restrict__ w, unsigned short* __restrict__ dst) {
  const int KT = CIN / 32, MT = COUTP / 16;
  const int total = 25 * KT * MT * 512;
  for (int idx = blockIdx.x * blockDim.x + threadIdx.x; idx < total;
       idx += gridDim.x * blockDim.x) {
    int j   = idx & 7;
    int l   = (idx >> 3) & 63;
    int blk = idx >> 9;
    int mt  = blk % MT;
    int rst = blk / MT;
    int kt  = rst % KT;
    int tap = rst / KT;
    int ky = tap / 5, kx = tap % 5;
    int co = mt * 16 + (l & 15);
    int ci = kt * 32 + (l >> 4) * 8 + j;
    float val = (co < COUT) ? w[((co * CIN + ci) * 5 + ky) * 5 + kx] : 0.0f;
    dst[idx] = f2bf(val);
  }
}

// ------------- upsample z2 x4 bilinear + concat y1 -> NHWC bf16 ------------
__global__ void upsample_cat_k(const float* __restrict__ z2,
                               const float* __restrict__ y1,
                               unsigned short* __restrict__ cat) {
  int tid = blockIdx.x * blockDim.x + threadIdx.x;
  int p = tid % 9216;
  int rest = tid / 9216;
  int chunk = rest % 40;
  int b = rest / 40;
  if (b >= 8) return;
  int Y = p / 96, X = p % 96;
  short8 vec;
  if (chunk < 16) {
    const float s = 23.0f / 95.0f;
    float ys = Y * s, xs = X * s;
    float fy = floorf(ys), fx = floorf(xs);
    int y0 = (int)fy, x0 = (int)fx;
    int y1i = min(y0 + 1, 23), x1i = min(x0 + 1, 23);
    float wy = ys - fy, wx = xs - fx;
    int c0 = chunk * 8;
    const float* zb = z2 + ((size_t)b * 128 + c0) * 576;
#pragma unroll
    for (int i = 0; i < 8; ++i) {
      const float* zc = zb + (size_t)i * 576;
      float g00 = zc[y0 * 24 + x0],  g01 = zc[y0 * 24 + x1i];
      float g10 = zc[y1i * 24 + x0], g11 = zc[y1i * 24 + x1i];
      float top = g00 + (g01 - g00) * wx;
      float bot = g10 + (g11 - g10) * wx;
      vec[i] = (short)f2bf(top + (bot - top) * wy);
    }
  } else {
    int c0 = (chunk - 16) * 8;
    const float* yb = y1 + ((size_t)b * 192 + c0) * 9216 + p;
#pragma unroll
    for (int i = 0; i < 8; ++i) vec[i] = (short)f2bf(yb[(size_t)i * 9216]);
  }
  int cbase = (chunk < 16) ? chunk * 8 : 128 + (chunk - 16) * 8;
  *reinterpret_cast<short8*>(cat + ((size_t)(b * 9216 + p)) * 320 + cbase) = vec;
}

// --------------------------- 5x5 conv, pad 2 --------------------------------
// Block: 256 thr = 4 waves; wave (wm, wp) = (co-half, px-half).
// Wave tile: 4 co-frags x 3 px-frags (64 co x 48 px) -> acc 48 regs.
// Block: 128 co x 1 row x 96 px. LDS: 32 KB (5 rows x 100 px x 32ci).
// stage->barrier->compute->barrier; 3 blocks/CU (reg-limited, LDS allows 5).
// Bijective XCD swizzle, coblk outermost (weight slice per-XCD L2-resident).
struct BranchArgs {
  const unsigned short* in[3];
  const unsigned short* w[3];
  const float* bias[3];
  unsigned short* ob[3];
  float* of[3];
};

template<int CIN, int COUT, int COUTP, int ACT0, int ACT1, int ACT2, int OUTMODE>
DEV void conv5_body(BranchArgs args, const char* __restrict__ zp) {
  const int KT = CIN / 32, MT = COUTP / 16;
  __shared__ alignas(16) char lds[32000];      // 2000 chunks x 16 B
  const int tid = threadIdx.x;                 // 0..255
  const int l = tid & 63;
  const int wid = tid >> 6;                    // 0..3
  const int wm = wid & 1;                      // co-half
  const int wp = wid >> 1;                     // px-half (0: x<48, 1: x>=48)
  const int lj = l >> 4, lx = l & 15;

  // ---- bijective XCD-aware block swizzle ----
  const int Zd = gridDim.y;                    // batch*branch count
  const int T = 96 * Zd * gridDim.z;           // total blocks (always %8==0)
  int f = blockIdx.x + 96 * (blockIdx.y + Zd * blockIdx.z);
  int fp = (f & 7) * (T >> 3) + (f >> 3);
  const int rowtile = fp % 96;                 // output row
  int rest = fp / 96;
  const int bz = rest % Zd;
  const int coblk = (rest / Zd) * 128;
  const int b = bz & 7, br = bz >> 3;
  const int y0 = rowtile;

  const unsigned short* act_in = args.in[br];
  const unsigned short* wfrag  = args.w[br];
  const int act = (br == 0) ? ACT0 : (br == 1 ? ACT1 : ACT2);

  // ---- per-thread staging descriptors (8 chunks of 16 B, 2000 total) ----
  int boff[8];
  unsigned okm = 0;
#pragma unroll
  for (int i = 0; i < 8; ++i) {
    int t = tid + i * 256;
    boff[i] = 0;
    if (t < 2000) {
      int p = t >> 2, q = t & 3;
      int r = p / 100, c = p - r * 100;
      int yy = y0 + r - 2, xx = c - 2;
      int ch = q ^ ((c >> 1) & 3);
      if ((unsigned)yy < 96u && (unsigned)xx < 96u) {
        boff[i] = ((b * 96 + yy) * 96 + xx) * CIN * 2 + ch * 16;
        okm |= 1u << i;
      }
    }
  }
  const char* actc = (const char*)act_in;

  f32x4 acc[4][3];
#pragma unroll
  for (int m = 0; m < 4; ++m)
#pragma unroll
    for (int n = 0; n < 3; ++n) acc[m][n] = f32x4{0.f, 0.f, 0.f, 0.f};

  auto stage = [&](int ktoff) {
#pragma unroll
    for (int i = 0; i < 8; ++i) {
      if (tid + i * 256 < 2000) {
        const char* s = ((okm >> i) & 1) ? (actc + boff[i] + ktoff) : zp;
        __builtin_amdgcn_global_load_lds(
            (const AS1 unsigned int*)s,
            (AS3 unsigned int*)(lds + (tid + i * 256) * 16), 16, 0, 0);
      }
    }
  };

  const int mt0 = (coblk >> 4) + wm * 4;
  for (int kt = 0; kt < KT; ++kt) {
    stage(kt * 64);       // prev-iter reads finished at loop-tail barrier
    __syncthreads();      // drains vmcnt -> buf staged
    const unsigned short* wb = wfrag + ((size_t)kt * MT + mt0) * 512 + l * 8;
#pragma unroll
    for (int ky = 0; ky < 5; ++ky) {
#pragma unroll
      for (int kx = 0; kx < 5; ++kx) {
        const int tap = ky * 5 + kx;
        short8 aW[4];
#pragma unroll
        for (int m = 0; m < 4; ++m)
          aW[m] = *reinterpret_cast<const short8*>(wb + ((size_t)tap * KT * MT + m) * 512);
#pragma unroll
        for (int n = 0; n < 3; ++n) {
          int c = kx + wp * 48 + n * 16 + lx;
          int off = ((ky * 100 + c) << 6) + ((lj ^ ((c >> 1) & 3)) << 4);
          short8 bA = *reinterpret_cast<const short8*>(lds + off);
#pragma unroll
          for (int m = 0; m < 4; ++m)
            acc[m][n] = __builtin_amdgcn_mfma_f32_16x16x32_bf16(aW[m], bA, acc[m][n], 0, 0, 0);
        }
      }
    }
    __syncthreads();      // all LDS reads done before next stage overwrites
  }

  const int yout = y0;
  if (OUTMODE == 0) {
    unsigned short* ob = args.ob[br];
#pragma unroll
    for (int m = 0; m < 4; ++m) {
      int co0 = coblk + wm * 64 + m * 16 + lj * 4;
      f32x4 bv = *reinterpret_cast<const f32x4*>(args.bias[br] + co0);
#pragma unroll
      for (int n = 0; n < 3; ++n) {
        int x = wp * 48 + n * 16 + lx;
        u16x4 pk;
#pragma unroll
        for (int j = 0; j < 4; ++j) {
          float v = acc[m][n][j] + bv[j];
          if (act == 1) v = fmaxf(v, 0.f);
          if (act == 2) v = (v >= 0.f) ? v : 0.01f * v;
          pk[j] = f2bf(v);
        }
        *reinterpret_cast<u16x4*>(ob + (size_t)((b * 96 + yout) * 96 + x) * COUT + co0) = pk;
      }
    }
  } else if (OUTMODE == 1) {
    // --- dense f32 NCHW epilogue: per-wave LDS slab (16co x 48px, stride 52) ---
    float* of = args.of[br];
    float* slab = reinterpret_cast<float*>(lds) + wid * 832 + 128; // 16x52 f32
    const int co_r = l >> 2;                   // 0..15
    const int xs   = (l & 3) * 12;             // 0,12,24,36
#pragma unroll
    for (int m = 0; m < 4; ++m) {
      int mco = coblk + wm * 64 + m * 16;
      if (mco < COUT) {
        f32x4 bv = *reinterpret_cast<const f32x4*>(args.bias[br] + mco + lj * 4);
#pragma unroll
        for (int n = 0; n < 3; ++n)
#pragma unroll
          for (int j = 0; j < 4; ++j) {
            float v = acc[m][n][j] + bv[j];
            if (act == 1) v = fmaxf(v, 0.f);
            if (act == 2) v = (v >= 0.f) ? v : 0.01f * v;
            slab[(lj * 4 + j) * 52 + n * 16 + lx] = v;
          }
        asm volatile("s_waitcnt lgkmcnt(0)" ::: "memory");
        __builtin_amdgcn_sched_barrier(0);
        const float* srow = slab + co_r * 52 + xs;
        float* drow = of + ((size_t)(b * COUT + mco + co_r) * 96 + yout) * 96 + wp * 48 + xs;
#pragma unroll
        for (int k = 0; k < 3; ++k)
          *reinterpret_cast<f32x4*>(drow + 4 * k) =
              *reinterpret_cast<const f32x4*>(srow + 4 * k);
        asm volatile("s_waitcnt lgkmcnt(0)" ::: "memory");
        __builtin_amdgcn_sched_barrier(0);
      }
    }
  } else {  // OUTMODE == 2: conv+bias -> per-(row, px-half) max partials
    float* part = args.of[0];
#pragma unroll
    for (int m = 0; m < 4; ++m) {
      int co0 = coblk + wm * 64 + m * 16 + lj * 4;
      f32x4 bv = f32x4{0.f, 0.f, 0.f, 0.f};
      if (co0 < COUT) bv = *reinterpret_cast<const f32x4*>(args.bias[br] + co0);
#pragma unroll
      for (int j = 0; j < 4; ++j) {
        float mx = -3.0e38f;
#pragma unroll
        for (int n = 0; n < 3; ++n) mx = fmaxf(mx, acc[m][n][j] + bv[j]);
#pragma unroll
        for (int s = 1; s < 16; s <<= 1) mx = fmaxf(mx, __shfl_xor(mx, s, 64));
        if (lx == 0 && co0 + j < COUT)
          part[(size_t)(b * COUT + co0 + j) * 192 + rowtile * 2 + wp] = mx;
      }
    }
  }
}

// ---- distinct kernel names per layer (profiler attribution) ----
__global__ __launch_bounds__(256, 3) void conv_l1(BranchArgs a, const char* __restrict__ zp) {
  conv5_body<320, 128, 128, 1, 2, 2, 0>(a, zp);
}
__global__ __launch_bounds__(256, 3) void conv_l2(BranchArgs a, const char* __restrict__ zp) {
  conv5_body<128, 128, 128, 1, 2, 0, 0>(a, zp);
}
__global__ __launch_bounds__(256, 3) void conv_l2w(BranchArgs a, const char* __restrict__ zp) {
  conv5_body<128, 576, 640, 0, 0, 0, 2>(a, zp);
}
__global__ __launch_bounds__(256, 3) void conv_l3(BranchArgs a, const char* __restrict__ zp) {
  conv5_body<128, 576, 640, 1, 0, 0, 1>(a, zp);
}

// --------------------- tail: reduce / 1x1 conv / softmax -------------------
__global__ void reduce_max_k(const float* __restrict__ part, float* __restrict__ pooled) {
  int i = blockIdx.x * blockDim.x + threadIdx.x;
  if (i >= 8 * 576) return;
  const float* p = part + (size_t)i * 192;
  float mx = p[0];
  for (int t = 1; t < 192; ++t) mx = fmaxf(mx, p[t]);
  pooled[i] = mx;
}

__global__ void tail_k(const float* __restrict__ pooled,
                       const float* __restrict__ ww3, const float* __restrict__ bw3,
                       float* __restrict__ outw) {
  __shared__ float g[576];
  __shared__ float h2[576];
  int b = blockIdx.x, tid = threadIdx.x;
  for (int i = tid; i < 576; i += 256) {
    float v = pooled[b * 576 + i];
    g[i] = (v >= 0.f) ? v : 0.01f * v;
  }
  __syncthreads();
  for (int o = tid; o < 576; o += 256) {
    float s = bw3[o];
    const float* wr = ww3 + (size_t)o * 576;
    for (int i = 0; i < 576; ++i) s += wr[i] * g[i];
    h2[o] = s;
  }
  __syncthreads();
  for (int m = tid; m < 192; m += 256) {
    float a0 = h2[m], a1 = h2[192 + m], a2 = h2[384 + m];
    float mx = fmaxf(a0, fmaxf(a1, a2));
    float e0 = expf(a0 - mx), e1 = expf(a1 - mx), e2 = expf(a2 - mx);
    float inv = 1.f / (e0 + e1 + e2);
    outw[b * 576 + m]       = e0 * inv;
    outw[b * 576 + 192 + m] = e1 * inv;
    outw[b * 576 + 384 + m] = e2 * inv;
  }
}

// ---------------------------------------------------------------------------
extern "C" void kernel_launch(void* const* d_in, const int* in_sizes, int n_in,
                              void* d_out, int out_size, void* d_ws, size_t ws_size,
                              hipStream_t stream) {
  const float* z2  = (const float*)d_in[0];
  const float* y1  = (const float*)d_in[1];
  const float* ws1 = (const float*)d_in[2];  const float* bs1 = (const float*)d_in[3];
  const float* ws2 = (const float*)d_in[4];  const float* bs2 = (const float*)d_in[5];
  const float* ws3 = (const float*)d_in[6];  const float* bs3 = (const float*)d_in[7];
  const float* wm1 = (const float*)d_in[8];  const float* bm1 = (const float*)d_in[9];
  const float* wm2 = (const float*)d_in[10]; const float* bm2 = (const float*)d_in[11];
  const float* wm3 = (const float*)d_in[12]; const float* bm3 = (const float*)d_in[13];
  const float* ww1 = (const float*)d_in[14]; const float* bw1 = (const float*)d_in[15];
  const float* ww2 = (const float*)d_in[16]; const float* bw2 = (const float*)d_in[17];
  const float* ww3 = (const float*)d_in[18]; const float* bw3 = (const float*)d_in[19];

  char* ws = (char*)d_ws;
  size_t off = 0;
  auto alloc = [&](size_t bytes) -> char* {
    char* p = ws + off;
    off += (bytes + 255) & ~(size_t)255;
    return p;
  };
  char* zp = alloc(4096);
  unsigned short* cat = (unsigned short*)alloc(8ull * 9216 * 320 * 2);
  unsigned short* t1s = (unsigned short*)alloc(8ull * 9216 * 128 * 2);
  unsigned short* t1m = (unsigned short*)alloc(8ull * 9216 * 128 * 2);
  unsigned short* t1w = (unsigned short*)alloc(8ull * 9216 * 128 * 2);
  const size_t szA = 25ull * 10 * 8 * 512;
  const size_t szB = 25ull * 4 * 8 * 512;
  const size_t szC = 25ull * 4 * 40 * 512;
  unsigned short* Ws1 = (unsigned short*)alloc(szA * 2);
  unsigned short* Ws2 = (unsigned short*)alloc(szB * 2);
  unsigned short* Ws3 = (unsigned short*)alloc(szC * 2);
  unsigned short* Wm1 = (unsigned short*)alloc(szA * 2);
  unsigned short* Wm2 = (unsigned short*)alloc(szB * 2);
  unsigned short* Wm3 = (unsigned short*)alloc(szC * 2);
  unsigned short* Ww1 = (unsigned short*)alloc(szA * 2);
  unsigned short* Ww2 = (unsigned short*)alloc(szC * 2);
  float* part   = (float*)alloc(8ull * 576 * 192 * 4);
  float* pooled = (float*)alloc(8ull * 576 * 4);
  // t2 buffers alias cat (fusedA finishes reading cat before fusedB writes t2)
  unsigned short* t2s = cat;
  unsigned short* t2m = cat + 8ull * 9216 * 128;

  float* out_sigma = (float*)d_out;
  float* out_means = out_sigma + 8ull * 576 * 9216;
  float* out_w     = out_means + 8ull * 576 * 9216;

  hipMemsetAsync(zp, 0, 4096, stream);

  prep_w<320, 128, 128><<<256, 256, 0, stream>>>(ws1, Ws1);
  prep_w<128, 128, 128><<<128, 256, 0, stream>>>(ws2, Ws2);
  prep_w<128, 576, 640><<<512, 256, 0, stream>>>(ws3, Ws3);
  prep_w<320, 128, 128><<<256, 256, 0, stream>>>(wm1, Wm1);
  prep_w<128, 128, 128><<<128, 256, 0, stream>>>(wm2, Wm2);
  prep_w<128, 576, 640><<<512, 256, 0, stream>>>(wm3, Wm3);
  prep_w<320, 128, 128><<<256, 256, 0, stream>>>(ww1, Ww1);
  prep_w<128, 576, 640><<<512, 256, 0, stream>>>(ww2, Ww2);

  upsample_cat_k<<<11520, 256, 0, stream>>>(z2, y1, cat);

  dim3 blk(256);

  // fused layer 1: sigma(relu) / means(lrelu) / weights(lrelu), cat -> t1*
  {
    BranchArgs a{};
    a.in[0] = cat; a.in[1] = cat; a.in[2] = cat;
    a.w[0] = Ws1; a.w[1] = Wm1; a.w[2] = Ww1;
    a.bias[0] = bs1; a.bias[1] = bm1; a.bias[2] = bw1;
    a.ob[0] = t1s; a.ob[1] = t1m; a.ob[2] = t1w;
    conv_l1<<<dim3(96, 24, 1), blk, 0, stream>>>(a, zp);
  }
  // fused layer 2: sigma(relu) / means(lrelu), t1* -> t2*
  {
    BranchArgs a{};
    a.in[0] = t1s; a.in[1] = t1m;
    a.w[0] = Ws2; a.w[1] = Wm2;
    a.bias[0] = bs2; a.bias[1] = bm2;
    a.ob[0] = t2s; a.ob[1] = t2m;
    conv_l2<<<dim3(96, 16, 1), blk, 0, stream>>>(a, zp);
  }
  // weights layer 2 conv + global-max partials (t1w -> part)
  {
    BranchArgs a{};
    a.in[0] = t1w;
    a.w[0] = Ww2;
    a.bias[0] = bw2;
    a.of[0] = part;
    conv_l2w<<<dim3(96, 8, 5), blk, 0, stream>>>(a, zp);
  }
  // fused layer 3: sigma(relu, f32) / means(none, f32), t2* -> d_out
  {
    BranchArgs a{};
    a.in[0] = t2s; a.in[1] = t2m;
    a.w[0] = Ws3; a.w[1] = Wm3;
    a.bias[0] = bs3; a.bias[1] = bm3;
    a.of[0] = out_sigma; a.of[1] = out_means;
    conv_l3<<<dim3(96, 16, 5), blk, 0, stream>>>(a, zp);
  }

  reduce_max_k<<<18, 256, 0, stream>>>(part, pooled);
  tail_k<<<8, 256, 0, stream>>>(pooled, ww3, bw3, out_w);
}